// Round 9
// baseline (1357.294 us; speedup 1.0000x reference)
//
#include <hip/hip_runtime.h>

#define TPB 256
#define NBLK 256          // blocks for edge-streaming kernels
#define BSH 8             // dst >> 8 -> bucket; 256 dsts per bucket

typedef __attribute__((ext_vector_type(4))) float f32x4;
typedef __attribute__((ext_vector_type(8))) short short8;

__device__ __forceinline__ unsigned short f2bf(float f) {
    unsigned u = __float_as_uint(f);
    u = (u + 0x7fffu + ((u >> 16) & 1u)) >> 16;
    return (unsigned short)u;
}
__device__ __forceinline__ float bflo(unsigned u) { return __uint_as_float(u << 16); }
__device__ __forceinline__ float bfhi(unsigned u) { return __uint_as_float(u & 0xffff0000u); }

// ============ pass A: per-block bucket histogram matrix (no global atomics) ====

__global__ __launch_bounds__(256) void k_bhist(const int* __restrict__ dst,
                                               int* __restrict__ blockhist, int E) {
    __shared__ int sh[512];
    int t = threadIdx.x;
    sh[t] = 0; sh[t + 256] = 0;
    __syncthreads();
    int chunk = (E + NBLK - 1) / NBLK;
    int lo = blockIdx.x * chunk;
    int hi = min(E, lo + chunk);
    for (int e = lo + t; e < hi; e += 256)
        atomicAdd(&sh[dst[e] >> BSH], 1);          // LDS atomic only
    __syncthreads();
    int* row = blockhist + blockIdx.x * 512;
    row[t] = sh[t];
    row[t + 256] = sh[t + 256];
}

// ============ pass B: column-sum + scan (1 block, 512 thr) ============

__global__ __launch_bounds__(512) void k_bscan(const int* __restrict__ blockhist,
                                               int* __restrict__ bbase, int* __restrict__ bcur,
                                               int E) {
    __shared__ int tmp[2][512];
    int t = threadIdx.x;
    int total = 0;
    #pragma unroll 8
    for (int b = 0; b < NBLK; ++b) total += blockhist[b * 512 + t];
    tmp[0][t] = total;
    __syncthreads();
    int sb = 0;
    for (int d = 1; d < 512; d <<= 1) {
        int val = tmp[sb][t] + ((t >= d) ? tmp[sb][t - d] : 0);
        tmp[sb ^ 1][t] = val;
        sb ^= 1;
        __syncthreads();
    }
    int excl = tmp[sb][t] - total;
    bbase[t] = excl;
    bcur[t] = excl;
    if (t == 0) bbase[512] = E;
}

// ============ pass C: scatter packed edges into bucket regions ============
// packed[e] = (src << 8) | (dst & 255); bucket id implicit in position.

__global__ __launch_bounds__(256) void k_bscatter(const int* __restrict__ src,
                                                  const int* __restrict__ dst,
                                                  int* __restrict__ bcur,
                                                  unsigned* __restrict__ packed,
                                                  int E, int NB) {
    __shared__ int sh[512];
    __shared__ int sbase[512];
    int t = threadIdx.x;
    sh[t] = 0; sh[t + 256] = 0;
    __syncthreads();
    int chunk = (E + NBLK - 1) / NBLK;
    int lo = blockIdx.x * chunk;
    int hi = min(E, lo + chunk);
    for (int e = lo + t; e < hi; e += 256)
        atomicAdd(&sh[dst[e] >> BSH], 1);
    __syncthreads();
    for (int i = t; i < NB; i += 256) {
        int c = sh[i];
        sbase[i] = c ? atomicAdd(&bcur[i], c) : 0;
    }
    __syncthreads();
    for (int i = t; i < NB; i += 256) sh[i] = sbase[i];
    __syncthreads();
    for (int e = lo + t; e < hi; e += 256) {
        int d = dst[e];
        int pos = atomicAdd(&sh[d >> BSH], 1);     // LDS atomic
        packed[pos] = ((unsigned)src[e] << 8) | (unsigned)(d & 255);
    }
}

// ============ pass D: per-bucket degree -> dinv (replaces full CSR) ============

__global__ __launch_bounds__(256) void k_dinv(const unsigned* __restrict__ packed,
                                              const int* __restrict__ bbase,
                                              float* __restrict__ dinv, int N) {
    __shared__ int hist[256];
    int b = blockIdx.x;
    int s0 = bbase[b], s1 = bbase[b + 1];
    int t = threadIdx.x;
    hist[t] = 0;
    __syncthreads();
    for (int e = s0 + t; e < s1; e += 256)
        atomicAdd(&hist[packed[e] & 255u], 1);     // LDS atomic
    __syncthreads();
    int d = (b << BSH) + t;
    if (d < N) dinv[d] = rsqrtf((float)hist[t] + 1.0f);
}

// ============ GEMM via MFMA, W cast fused into LDS staging ============
// g[i][j] = bf16( dinv[i] * sum_k x[i][k]*W[j][k] )

__global__ __launch_bounds__(256) void k_gemm(const float* __restrict__ x,
                                              const float* __restrict__ W,
                                              const float* __restrict__ dinv,
                                              unsigned short* __restrict__ g, int n) {
    __shared__ unsigned short wb[128][136];
    const int tid = threadIdx.x;

    for (int chunk = tid; chunk < 2048; chunk += 256) {
        int nrow = chunk >> 4, k8 = (chunk & 15) << 3;
        const float* wp = W + nrow * 128 + k8;
        float4 w0 = *(const float4*)wp;
        float4 w1 = *(const float4*)(wp + 4);
        union { unsigned short u[8]; uint4 q; } pk;
        pk.u[0] = f2bf(w0.x); pk.u[1] = f2bf(w0.y); pk.u[2] = f2bf(w0.z); pk.u[3] = f2bf(w0.w);
        pk.u[4] = f2bf(w1.x); pk.u[5] = f2bf(w1.y); pk.u[6] = f2bf(w1.z); pk.u[7] = f2bf(w1.w);
        *(uint4*)&wb[nrow][k8] = pk.q;
    }
    __syncthreads();

    const int lane = tid & 63;
    const int wid  = tid >> 6;
    const int l15  = lane & 15;
    const int quad = lane >> 4;
    const int row  = blockIdx.x * 64 + wid * 16 + l15;
    const int rowc = (row < n) ? row : (n - 1);

    f32x4 acc[8];
    #pragma unroll
    for (int t = 0; t < 8; ++t) acc[t] = (f32x4){0.f, 0.f, 0.f, 0.f};

    #pragma unroll
    for (int ks = 0; ks < 4; ++ks) {
        const int kb = ks * 32 + quad * 8;
        float4 a0 = *(const float4*)(x + (long)rowc * 128 + kb);
        float4 a1 = *(const float4*)(x + (long)rowc * 128 + kb + 4);
        union { unsigned short u[8]; short8 v; } af;
        af.u[0] = f2bf(a0.x); af.u[1] = f2bf(a0.y); af.u[2] = f2bf(a0.z); af.u[3] = f2bf(a0.w);
        af.u[4] = f2bf(a1.x); af.u[5] = f2bf(a1.y); af.u[6] = f2bf(a1.z); af.u[7] = f2bf(a1.w);
        #pragma unroll
        for (int t = 0; t < 8; ++t) {
            short8 bf = *(const short8*)&wb[t * 16 + l15][kb];
            acc[t] = __builtin_amdgcn_mfma_f32_16x16x32_bf16(af.v, bf, acc[t], 0, 0, 0);
        }
    }

    int   orow[4];
    float dv[4];
    #pragma unroll
    for (int r = 0; r < 4; ++r) {
        orow[r] = blockIdx.x * 64 + wid * 16 + quad * 4 + r;
        dv[r]   = (orow[r] < n) ? dinv[orow[r]] : 0.f;
    }
    #pragma unroll
    for (int t = 0; t < 8; ++t) {
        int col = t * 16 + l15;
        #pragma unroll
        for (int r = 0; r < 4; ++r) {
            if (orow[r] < n)
                g[(long)orow[r] * 128 + col] = f2bf(acc[t][r] * dv[r]);
        }
    }
}

// ============ aggregate: bucket-owned LDS accumulators, XCD-pinned slices ======
// Block = (bucket B = blockIdx>>2, slice S = blockIdx&3). Round-robin block->XCD
// means slice S lives on XCDs {S, S+4} only -> each XCD fetches just its 64B
// column slice of g (8x less redundant L2 fill). Edges stream unordered; no
// per-dst divergence. acc padded to 33 cols so same-col different-dst atomics
// spread across banks.

__global__ __launch_bounds__(256) void k_agg(const unsigned* __restrict__ packed,
                                             const int* __restrict__ bbase,
                                             const unsigned short* __restrict__ g,
                                             const float* __restrict__ dinv,
                                             const float* __restrict__ bias,
                                             float* __restrict__ out, int N) {
    __shared__ float acc[256][33];
    __shared__ unsigned batch[256];
    const int B = blockIdx.x >> 2;
    const int S = blockIdx.x & 3;
    const int t = threadIdx.x;
    const int sub = t & 7;                 // column part (0..7)
    const int colb = S * 32 + sub * 4;     // base bf16 column for this lane

    for (int i = t; i < 256 * 33; i += 256) (&acc[0][0])[i] = 0.f;

    const int s0 = bbase[B], s1 = bbase[B + 1];
    __syncthreads();

    for (int base = s0; base < s1; base += 256) {
        int m = min(256, s1 - base);
        if (t < m) batch[t] = packed[base + t];
        __syncthreads();
        #pragma unroll
        for (int p = 0; p < 8; ++p) {
            int el = (t >> 3) + (p << 5);          // 32 edges per pass
            if (el < m) {
                unsigned pk = batch[el];           // 8-lane LDS broadcast
                int d8 = pk & 255u;
                int s  = pk >> 8;
                uint2 gv = *(const uint2*)(g + (long)s * 128 + colb);
                atomicAdd(&acc[d8][sub * 4 + 0], bflo(gv.x));
                atomicAdd(&acc[d8][sub * 4 + 1], bfhi(gv.x));
                atomicAdd(&acc[d8][sub * 4 + 2], bflo(gv.y));
                atomicAdd(&acc[d8][sub * 4 + 3], bfhi(gv.y));
            }
        }
        __syncthreads();
    }

    // epilogue: 8 lanes per dst, 32 dsts per pass
    #pragma unroll
    for (int p = 0; p < 8; ++p) {
        int d8 = (t >> 3) + (p << 5);
        int d = (B << BSH) + d8;
        if (d < N) {
            uint2 gs = *(const uint2*)(g + (long)d * 128 + colb);  // self-loop
            float sc = dinv[d];
            float4 bb = *(const float4*)(bias + colb);
            float4 r;
            r.x = (acc[d8][sub * 4 + 0] + bflo(gs.x)) * sc + bb.x;
            r.y = (acc[d8][sub * 4 + 1] + bfhi(gs.x)) * sc + bb.y;
            r.z = (acc[d8][sub * 4 + 2] + bflo(gs.y)) * sc + bb.z;
            r.w = (acc[d8][sub * 4 + 3] + bfhi(gs.y)) * sc + bb.w;
            *(float4*)(out + (long)d * 128 + colb) = r;
        }
    }
}

// ============ launch ============

extern "C" void kernel_launch(void* const* d_in, const int* in_sizes, int n_in,
                              void* d_out, int out_size, void* d_ws, size_t ws_size,
                              hipStream_t stream) {
    const float* x  = (const float*)d_in[0];
    const int*   ei = (const int*)d_in[1];
    // d_in[2] = edge_attr (unused; GCN edge weight = 1)
    const float* W  = (const float*)d_in[3];
    const float* b  = (const float*)d_in[4];
    float* out = (float*)d_out;

    const int N = in_sizes[0] / 128;
    const int E = in_sizes[1] / 2;
    const int* src = ei;
    const int* dst = ei + E;
    const int NB = (N + 255) >> BSH;   // 391 buckets (<= 512)

    // ---- workspace carve (~33 MB) ----
    char* p = (char*)d_ws;
    auto carve = [&](size_t bytes) { char* q = p; p += (bytes + 255) & ~(size_t)255; return q; };
    int*            blockhist = (int*)           carve((size_t)NBLK * 512 * 4);
    int*            bbase     = (int*)           carve(513 * 4);
    int*            bcur      = (int*)           carve(512 * 4);
    float*          dinv      = (float*)         carve((size_t)N * 4);
    unsigned*       packed    = (unsigned*)      carve((size_t)E * 4);
    unsigned short* g         = (unsigned short*)carve((size_t)N * 128 * 2);

    k_bhist   <<<NBLK, TPB, 0, stream>>>(dst, blockhist, E);
    k_bscan   <<<1, 512, 0, stream>>>(blockhist, bbase, bcur, E);
    k_bscatter<<<NBLK, TPB, 0, stream>>>(src, dst, bcur, packed, E, NB);
    k_dinv    <<<NB, TPB, 0, stream>>>(packed, bbase, dinv, N);

    k_gemm<<<(N + 63) / 64, TPB, 0, stream>>>(x, W, dinv, g, N);

    k_agg<<<NB * 4, TPB, 0, stream>>>(packed, bbase, g, dinv, b, out, N);
}

// Round 10
// 253.586 us; speedup vs baseline: 5.3524x; 5.3524x over previous
//
#include <hip/hip_runtime.h>

#define TPB 256
#define NBLK 256          // blocks for edge-streaming kernels
#define BSH 8             // dst >> 8 -> bucket; 256 dsts per bucket

typedef __attribute__((ext_vector_type(4))) float f32x4;
typedef __attribute__((ext_vector_type(8))) short short8;

__device__ __forceinline__ unsigned short f2bf(float f) {
    unsigned u = __float_as_uint(f);
    u = (u + 0x7fffu + ((u >> 16) & 1u)) >> 16;
    return (unsigned short)u;
}
__device__ __forceinline__ float bflo(unsigned u) { return __uint_as_float(u << 16); }
__device__ __forceinline__ float bfhi(unsigned u) { return __uint_as_float(u & 0xffff0000u); }

// ============ pass A: per-block bucket histogram matrix (no global atomics) ====

__global__ __launch_bounds__(256) void k_bhist(const int* __restrict__ dst,
                                               int* __restrict__ blockhist, int E) {
    __shared__ int sh[512];
    int t = threadIdx.x;
    sh[t] = 0; sh[t + 256] = 0;
    __syncthreads();
    int chunk = (E + NBLK - 1) / NBLK;
    int lo = blockIdx.x * chunk;
    int hi = min(E, lo + chunk);
    for (int e = lo + t; e < hi; e += 256)
        atomicAdd(&sh[dst[e] >> BSH], 1);          // LDS atomic only
    __syncthreads();
    int* row = blockhist + blockIdx.x * 512;
    row[t] = sh[t];
    row[t + 256] = sh[t + 256];
}

// ============ pass B: column prefix + bucket scan (1 block, 512 thr) ============
// Rewrites blockhist[b][k] to the EXCLUSIVE prefix over blocks b'<b (thread t
// owns column t), so k_bscatter gets its base with zero atomics. Then scans
// bucket totals into bbase.

__global__ __launch_bounds__(512) void k_bscan(int* __restrict__ blockhist,
                                               int* __restrict__ bbase, int E) {
    __shared__ int tmp[2][512];
    int t = threadIdx.x;
    int run = 0;
    for (int b = 0; b < NBLK; ++b) {
        int v = blockhist[b * 512 + t];
        blockhist[b * 512 + t] = run;              // exclusive per-block prefix
        run += v;
    }
    tmp[0][t] = run;                               // column total
    __syncthreads();
    int sb = 0;
    for (int d = 1; d < 512; d <<= 1) {
        int val = tmp[sb][t] + ((t >= d) ? tmp[sb][t - d] : 0);
        tmp[sb ^ 1][t] = val;
        sb ^= 1;
        __syncthreads();
    }
    bbase[t] = tmp[sb][t] - run;                   // exclusive bucket base
    if (t == 0) bbase[512] = E;
}

// ============ pass C: scatter packed edges (no re-histogram, no global atomics) =
// packed[e] = (src << 8) | (dst & 255); bucket id implicit in position.

__global__ __launch_bounds__(256) void k_bscatter(const int* __restrict__ src,
                                                  const int* __restrict__ dst,
                                                  const int* __restrict__ blockhist,
                                                  const int* __restrict__ bbase,
                                                  unsigned* __restrict__ packed, int E) {
    __shared__ int sh[512];
    int t = threadIdx.x;
    const int* row = blockhist + blockIdx.x * 512;
    sh[t]       = bbase[t]       + row[t];
    sh[t + 256] = bbase[t + 256] + row[t + 256];
    __syncthreads();
    int chunk = (E + NBLK - 1) / NBLK;
    int lo = blockIdx.x * chunk;
    int hi = min(E, lo + chunk);
    for (int e = lo + t; e < hi; e += 256) {
        int d = dst[e];
        int pos = atomicAdd(&sh[d >> BSH], 1);     // LDS atomic
        packed[pos] = ((unsigned)src[e] << 8) | (unsigned)(d & 255);
    }
}

// ============ pass D: per-bucket exact CSR + offsets + dinv ============

__global__ __launch_bounds__(256) void k_bcsr(const unsigned* __restrict__ packed,
                                              const int* __restrict__ bbase,
                                              int* __restrict__ offsets,
                                              int* __restrict__ sorted_src,
                                              float* __restrict__ dinv, int N, int E) {
    __shared__ int hist[256];
    __shared__ int tmp[2][256];
    __shared__ int scur[256];
    int b = blockIdx.x;
    int s0 = bbase[b], s1 = bbase[b + 1];
    int t = threadIdx.x;
    hist[t] = 0;
    __syncthreads();
    for (int e = s0 + t; e < s1; e += 256)
        atomicAdd(&hist[packed[e] & 255u], 1);     // LDS atomic
    __syncthreads();
    int v = hist[t];
    tmp[0][t] = v;
    __syncthreads();
    int sb = 0;
    for (int d = 1; d < 256; d <<= 1) {
        int val = tmp[sb][t] + ((t >= d) ? tmp[sb][t - d] : 0);
        tmp[sb ^ 1][t] = val;
        sb ^= 1;
        __syncthreads();
    }
    int gbase = s0 + (tmp[sb][t] - v);
    scur[t] = gbase;
    int d = (b << BSH) + t;
    if (d < N) { offsets[d] = gbase; dinv[d] = rsqrtf((float)v + 1.0f); }
    if (b == 0 && t == 0) offsets[N] = E;
    __syncthreads();
    for (int e = s0 + t; e < s1; e += 256) {
        unsigned pk = packed[e];
        int pos = atomicAdd(&scur[pk & 255u], 1);  // LDS atomic
        sorted_src[pos] = (int)(pk >> 8);
    }
}

// ============ GEMM via MFMA, W cast fused into LDS staging ============
// g[i][j] = bf16( dinv[i] * sum_k x[i][k]*W[j][k] )

__global__ __launch_bounds__(256) void k_gemm(const float* __restrict__ x,
                                              const float* __restrict__ W,
                                              const float* __restrict__ dinv,
                                              unsigned short* __restrict__ g, int n) {
    __shared__ unsigned short wb[128][136];
    const int tid = threadIdx.x;

    for (int chunk = tid; chunk < 2048; chunk += 256) {
        int nrow = chunk >> 4, k8 = (chunk & 15) << 3;
        const float* wp = W + nrow * 128 + k8;
        float4 w0 = *(const float4*)wp;
        float4 w1 = *(const float4*)(wp + 4);
        union { unsigned short u[8]; uint4 q; } pk;
        pk.u[0] = f2bf(w0.x); pk.u[1] = f2bf(w0.y); pk.u[2] = f2bf(w0.z); pk.u[3] = f2bf(w0.w);
        pk.u[4] = f2bf(w1.x); pk.u[5] = f2bf(w1.y); pk.u[6] = f2bf(w1.z); pk.u[7] = f2bf(w1.w);
        *(uint4*)&wb[nrow][k8] = pk.q;
    }
    __syncthreads();

    const int lane = tid & 63;
    const int wid  = tid >> 6;
    const int l15  = lane & 15;
    const int quad = lane >> 4;
    const int row  = blockIdx.x * 64 + wid * 16 + l15;
    const int rowc = (row < n) ? row : (n - 1);

    f32x4 acc[8];
    #pragma unroll
    for (int t = 0; t < 8; ++t) acc[t] = (f32x4){0.f, 0.f, 0.f, 0.f};

    #pragma unroll
    for (int ks = 0; ks < 4; ++ks) {
        const int kb = ks * 32 + quad * 8;
        float4 a0 = *(const float4*)(x + (long)rowc * 128 + kb);
        float4 a1 = *(const float4*)(x + (long)rowc * 128 + kb + 4);
        union { unsigned short u[8]; short8 v; } af;
        af.u[0] = f2bf(a0.x); af.u[1] = f2bf(a0.y); af.u[2] = f2bf(a0.z); af.u[3] = f2bf(a0.w);
        af.u[4] = f2bf(a1.x); af.u[5] = f2bf(a1.y); af.u[6] = f2bf(a1.z); af.u[7] = f2bf(a1.w);
        #pragma unroll
        for (int t = 0; t < 8; ++t) {
            short8 bf = *(const short8*)&wb[t * 16 + l15][kb];
            acc[t] = __builtin_amdgcn_mfma_f32_16x16x32_bf16(af.v, bf, acc[t], 0, 0, 0);
        }
    }

    int   orow[4];
    float dv[4];
    #pragma unroll
    for (int r = 0; r < 4; ++r) {
        orow[r] = blockIdx.x * 64 + wid * 16 + quad * 4 + r;
        dv[r]   = (orow[r] < n) ? dinv[orow[r]] : 0.f;
    }
    #pragma unroll
    for (int t = 0; t < 8; ++t) {
        int col = t * 16 + l15;
        #pragma unroll
        for (int r = 0; r < 4; ++r) {
            if (orow[r] < n)
                g[(long)orow[r] * 128 + col] = f2bf(acc[t][r] * dv[r]);
        }
    }
}

// ============ CSR aggregate: out[d] = dinv[d]*(g[d] + sum g[src]) + b ============
// 32 lanes per dst; 8/4/1 unroll ladder (R5 config: VGPR 24, ~70% occ, 64 us).

__global__ __launch_bounds__(256) void k_aggregate(const int* __restrict__ sorted_src,
                                                   const int* __restrict__ offsets,
                                                   const unsigned short* __restrict__ g,
                                                   const float* __restrict__ dinv,
                                                   const float* __restrict__ b,
                                                   float* __restrict__ out, int n) {
    int d = blockIdx.x * (TPB / 32) + (threadIdx.x >> 5);
    if (d >= n) return;
    int c = (threadIdx.x & 31) << 2;

    int s0 = offsets[d];
    int s1 = offsets[d + 1];

    float4 acc = make_float4(0.f, 0.f, 0.f, 0.f);
    auto addrow = [&](int r) {
        uint2 p = *(const uint2*)(g + (long)r * 128 + c);
        acc.x += bflo(p.x); acc.y += bfhi(p.x);
        acc.z += bflo(p.y); acc.w += bfhi(p.y);
    };

    addrow(d);  // self-loop
    int e = s0;
    for (; e + 8 <= s1; e += 8) {
        int a[8];
        #pragma unroll
        for (int j = 0; j < 8; ++j) a[j] = sorted_src[e + j];
        #pragma unroll
        for (int j = 0; j < 8; ++j) addrow(a[j]);
    }
    for (; e + 4 <= s1; e += 4) {
        int a[4];
        #pragma unroll
        for (int j = 0; j < 4; ++j) a[j] = sorted_src[e + j];
        #pragma unroll
        for (int j = 0; j < 4; ++j) addrow(a[j]);
    }
    for (; e < s1; ++e) addrow(sorted_src[e]);

    float s = dinv[d];
    float4 bb = *(const float4*)(b + c);
    float4 r = make_float4(acc.x * s + bb.x, acc.y * s + bb.y,
                           acc.z * s + bb.z, acc.w * s + bb.w);
    *(float4*)(out + (long)d * 128 + c) = r;
}

// ============ launch ============

extern "C" void kernel_launch(void* const* d_in, const int* in_sizes, int n_in,
                              void* d_out, int out_size, void* d_ws, size_t ws_size,
                              hipStream_t stream) {
    const float* x  = (const float*)d_in[0];
    const int*   ei = (const int*)d_in[1];
    // d_in[2] = edge_attr (unused; GCN edge weight = 1)
    const float* W  = (const float*)d_in[3];
    const float* b  = (const float*)d_in[4];
    float* out = (float*)d_out;

    const int N = in_sizes[0] / 128;
    const int E = in_sizes[1] / 2;
    const int* src = ei;
    const int* dst = ei + E;
    const int NB = (N + 255) >> BSH;   // 391 buckets (<= 512)

    // ---- workspace carve (~40 MB) ----
    char* p = (char*)d_ws;
    auto carve = [&](size_t bytes) { char* q = p; p += (bytes + 255) & ~(size_t)255; return q; };
    int*            blockhist  = (int*)           carve((size_t)NBLK * 512 * 4);
    int*            bbase      = (int*)           carve(513 * 4);
    int*            offsets    = (int*)           carve((size_t)(N + 1) * 4);
    float*          dinv       = (float*)         carve((size_t)N * 4);
    unsigned*       packed     = (unsigned*)      carve((size_t)E * 4);
    int*            sorted_src = (int*)           carve((size_t)E * 4);
    unsigned short* g          = (unsigned short*)carve((size_t)N * 128 * 2);

    k_bhist   <<<NBLK, TPB, 0, stream>>>(dst, blockhist, E);
    k_bscan   <<<1, 512, 0, stream>>>(blockhist, bbase, E);
    k_bscatter<<<NBLK, TPB, 0, stream>>>(src, dst, blockhist, bbase, packed, E);
    k_bcsr    <<<NB, TPB, 0, stream>>>(packed, bbase, offsets, sorted_src, dinv, N, E);

    k_gemm<<<(N + 63) / 64, TPB, 0, stream>>>(x, W, dinv, g, N);

    k_aggregate<<<(N + (TPB / 32) - 1) / (TPB / 32), TPB, 0, stream>>>(
        sorted_src, offsets, g, dinv, b, out, N);
}

// Round 11
// 243.114 us; speedup vs baseline: 5.5829x; 1.0431x over previous
//
#include <hip/hip_runtime.h>

#define TPB 256
#define NBLK 256          // blocks for edge-streaming kernels
#define BSH 8             // dst >> 8 -> bucket; 256 dsts per bucket
#define BCAP 6144         // LDS staging cap per bucket (mean 4092, +4sigma ~4350)

typedef __attribute__((ext_vector_type(4))) float f32x4;
typedef __attribute__((ext_vector_type(8))) short short8;

__device__ __forceinline__ unsigned short f2bf(float f) {
    unsigned u = __float_as_uint(f);
    u = (u + 0x7fffu + ((u >> 16) & 1u)) >> 16;
    return (unsigned short)u;
}
__device__ __forceinline__ float bflo(unsigned u) { return __uint_as_float(u << 16); }
__device__ __forceinline__ float bfhi(unsigned u) { return __uint_as_float(u & 0xffff0000u); }

// ============ pass A: per-block bucket histogram matrix (no global atomics) ====

__global__ __launch_bounds__(256) void k_bhist(const int* __restrict__ dst,
                                               int* __restrict__ blockhist, int E) {
    __shared__ int sh[512];
    int t = threadIdx.x;
    sh[t] = 0; sh[t + 256] = 0;
    __syncthreads();
    int chunk = (E + NBLK - 1) / NBLK;
    int lo = blockIdx.x * chunk;
    int hi = min(E, lo + chunk);
    for (int e = lo + t; e < hi; e += 256)
        atomicAdd(&sh[dst[e] >> BSH], 1);          // LDS atomic only
    __syncthreads();
    int* row = blockhist + blockIdx.x * 512;
    row[t] = sh[t];
    row[t + 256] = sh[t + 256];
}

// ============ pass B: column prefix + bucket scan (1 block, 512 thr) ============
// 8-wide load/store phases pipeline what was a serial 256-iter dependent loop.

__global__ __launch_bounds__(512) void k_bscan(int* __restrict__ blockhist,
                                               int* __restrict__ bbase, int E) {
    __shared__ int tmp[2][512];
    int t = threadIdx.x;
    int run = 0;
    for (int b = 0; b < NBLK; b += 8) {
        int v[8];
        #pragma unroll
        for (int j = 0; j < 8; ++j) v[j] = blockhist[(b + j) * 512 + t];  // 8 in flight
        #pragma unroll
        for (int j = 0; j < 8; ++j) { blockhist[(b + j) * 512 + t] = run; run += v[j]; }
    }
    tmp[0][t] = run;                               // column total
    __syncthreads();
    int sb = 0;
    for (int d = 1; d < 512; d <<= 1) {
        int val = tmp[sb][t] + ((t >= d) ? tmp[sb][t - d] : 0);
        tmp[sb ^ 1][t] = val;
        sb ^= 1;
        __syncthreads();
    }
    bbase[t] = tmp[sb][t] - run;                   // exclusive bucket base
    if (t == 0) bbase[512] = E;
}

// ============ pass C: scatter packed edges (no re-histogram, no global atomics) =
// packed[e] = (src << 8) | (dst & 255); bucket id implicit in position.

__global__ __launch_bounds__(256) void k_bscatter(const int* __restrict__ src,
                                                  const int* __restrict__ dst,
                                                  const int* __restrict__ blockhist,
                                                  const int* __restrict__ bbase,
                                                  unsigned* __restrict__ packed, int E) {
    __shared__ int sh[512];
    int t = threadIdx.x;
    const int* row = blockhist + blockIdx.x * 512;
    sh[t]       = bbase[t]       + row[t];
    sh[t + 256] = bbase[t + 256] + row[t + 256];
    __syncthreads();
    int chunk = (E + NBLK - 1) / NBLK;
    int lo = blockIdx.x * chunk;
    int hi = min(E, lo + chunk);
    for (int e = lo + t; e < hi; e += 256) {
        int d = dst[e];
        int pos = atomicAdd(&sh[d >> BSH], 1);     // LDS atomic
        packed[pos] = ((unsigned)src[e] << 8) | (unsigned)(d & 255);
    }
}

// ============ pass D: per-bucket exact CSR + offsets + dinv ============
// Sorted edges staged in LDS so the global sorted_src write is coalesced.
// Fallback path (never taken at this E/N) keeps correctness if a bucket > BCAP.

__global__ __launch_bounds__(256) void k_bcsr(const unsigned* __restrict__ packed,
                                              const int* __restrict__ bbase,
                                              int* __restrict__ offsets,
                                              int* __restrict__ sorted_src,
                                              float* __restrict__ dinv, int N, int E) {
    __shared__ int hist[256];
    __shared__ int tmp[2][256];
    __shared__ int scur[256];
    __shared__ unsigned stage[BCAP];
    int b = blockIdx.x;
    int s0 = bbase[b], s1 = bbase[b + 1];
    int cnt = s1 - s0;
    int t = threadIdx.x;
    hist[t] = 0;
    __syncthreads();
    for (int e = s0 + t; e < s1; e += 256)
        atomicAdd(&hist[packed[e] & 255u], 1);     // LDS atomic
    __syncthreads();
    int v = hist[t];
    tmp[0][t] = v;
    __syncthreads();
    int sb = 0;
    for (int d = 1; d < 256; d <<= 1) {
        int val = tmp[sb][t] + ((t >= d) ? tmp[sb][t - d] : 0);
        tmp[sb ^ 1][t] = val;
        sb ^= 1;
        __syncthreads();
    }
    int lbase = tmp[sb][t] - v;                    // bucket-local exclusive base
    scur[t] = lbase;
    int d = (b << BSH) + t;
    if (d < N) { offsets[d] = s0 + lbase; dinv[d] = rsqrtf((float)v + 1.0f); }
    if (b == 0 && t == 0) offsets[N] = E;
    __syncthreads();
    if (cnt <= BCAP) {
        for (int e = s0 + t; e < s1; e += 256) {
            unsigned pk = packed[e];
            int pos = atomicAdd(&scur[pk & 255u], 1);  // LDS atomic
            stage[pos] = pk >> 8;                      // LDS scatter
        }
        __syncthreads();
        for (int i = t; i < cnt; i += 256)
            sorted_src[s0 + i] = (int)stage[i];        // coalesced stream-out
    } else {
        for (int e = s0 + t; e < s1; e += 256) {
            unsigned pk = packed[e];
            int pos = atomicAdd(&scur[pk & 255u], 1);
            sorted_src[(long)s0 + pos] = (int)(pk >> 8);
        }
    }
}

// ============ GEMM via MFMA (swapped operands -> transposed D) ============
// g[i][j] = bf16( dinv[i] * sum_k x[i][k]*W[j][k] ).
// A-operand = W frag, B-operand = x frag (identical lane layouts: 8 contiguous
// k at (l15, quad*8)). D then has col(l15)=x-row i, row(quad*4+r)=W-row j, so
// each lane owns 4 CONSECUTIVE g columns -> one packed uint2 store per tile
// (8 stores/thread vs 32 scalar), and dinv is one load/thread.

__global__ __launch_bounds__(256) void k_gemm(const float* __restrict__ x,
                                              const float* __restrict__ W,
                                              const float* __restrict__ dinv,
                                              unsigned short* __restrict__ g, int n) {
    __shared__ unsigned short wb[128][136];
    const int tid = threadIdx.x;

    for (int chunk = tid; chunk < 2048; chunk += 256) {
        int nrow = chunk >> 4, k8 = (chunk & 15) << 3;
        const float* wp = W + nrow * 128 + k8;
        float4 w0 = *(const float4*)wp;
        float4 w1 = *(const float4*)(wp + 4);
        union { unsigned short u[8]; uint4 q; } pk;
        pk.u[0] = f2bf(w0.x); pk.u[1] = f2bf(w0.y); pk.u[2] = f2bf(w0.z); pk.u[3] = f2bf(w0.w);
        pk.u[4] = f2bf(w1.x); pk.u[5] = f2bf(w1.y); pk.u[6] = f2bf(w1.z); pk.u[7] = f2bf(w1.w);
        *(uint4*)&wb[nrow][k8] = pk.q;
    }
    __syncthreads();

    const int lane = tid & 63;
    const int wid  = tid >> 6;
    const int l15  = lane & 15;
    const int quad = lane >> 4;
    const int row  = blockIdx.x * 64 + wid * 16 + l15;
    const int rowc = (row < n) ? row : (n - 1);

    f32x4 acc[8];
    #pragma unroll
    for (int t = 0; t < 8; ++t) acc[t] = (f32x4){0.f, 0.f, 0.f, 0.f};

    #pragma unroll
    for (int ks = 0; ks < 4; ++ks) {
        const int kb = ks * 32 + quad * 8;
        float4 a0 = *(const float4*)(x + (long)rowc * 128 + kb);
        float4 a1 = *(const float4*)(x + (long)rowc * 128 + kb + 4);
        union { unsigned short u[8]; short8 v; } af;
        af.u[0] = f2bf(a0.x); af.u[1] = f2bf(a0.y); af.u[2] = f2bf(a0.z); af.u[3] = f2bf(a0.w);
        af.u[4] = f2bf(a1.x); af.u[5] = f2bf(a1.y); af.u[6] = f2bf(a1.z); af.u[7] = f2bf(a1.w);
        #pragma unroll
        for (int t = 0; t < 8; ++t) {
            short8 bf = *(const short8*)&wb[t * 16 + l15][kb];
            // swapped: W frag as A, x frag as B  ->  D[j][i]
            acc[t] = __builtin_amdgcn_mfma_f32_16x16x32_bf16(bf, af.v, acc[t], 0, 0, 0);
        }
    }

    if (row < n) {
        float dv = dinv[row];
        unsigned short* gp = g + (long)row * 128 + quad * 4;
        #pragma unroll
        for (int t = 0; t < 8; ++t) {
            unsigned short u0 = f2bf(acc[t][0] * dv);
            unsigned short u1 = f2bf(acc[t][1] * dv);
            unsigned short u2 = f2bf(acc[t][2] * dv);
            unsigned short u3 = f2bf(acc[t][3] * dv);
            uint2 pk;
            pk.x = (unsigned)u0 | ((unsigned)u1 << 16);
            pk.y = (unsigned)u2 | ((unsigned)u3 << 16);
            *(uint2*)(gp + t * 16) = pk;          // 4 consecutive bf16 cols
        }
    }
}

// ============ CSR aggregate: out[d] = dinv[d]*(g[d] + sum g[src]) + b ============
// 32 lanes per dst; 8/4/1 unroll ladder (VGPR 24, ~70% occ — R5/R9 config).

__global__ __launch_bounds__(256) void k_aggregate(const int* __restrict__ sorted_src,
                                                   const int* __restrict__ offsets,
                                                   const unsigned short* __restrict__ g,
                                                   const float* __restrict__ dinv,
                                                   const float* __restrict__ b,
                                                   float* __restrict__ out, int n) {
    int d = blockIdx.x * (TPB / 32) + (threadIdx.x >> 5);
    if (d >= n) return;
    int c = (threadIdx.x & 31) << 2;

    int s0 = offsets[d];
    int s1 = offsets[d + 1];

    float4 acc = make_float4(0.f, 0.f, 0.f, 0.f);
    auto addrow = [&](int r) {
        uint2 p = *(const uint2*)(g + (long)r * 128 + c);
        acc.x += bflo(p.x); acc.y += bfhi(p.x);
        acc.z += bflo(p.y); acc.w += bfhi(p.y);
    };

    addrow(d);  // self-loop
    int e = s0;
    for (; e + 8 <= s1; e += 8) {
        int a[8];
        #pragma unroll
        for (int j = 0; j < 8; ++j) a[j] = sorted_src[e + j];
        #pragma unroll
        for (int j = 0; j < 8; ++j) addrow(a[j]);
    }
    for (; e + 4 <= s1; e += 4) {
        int a[4];
        #pragma unroll
        for (int j = 0; j < 4; ++j) a[j] = sorted_src[e + j];
        #pragma unroll
        for (int j = 0; j < 4; ++j) addrow(a[j]);
    }
    for (; e < s1; ++e) addrow(sorted_src[e]);

    float s = dinv[d];
    float4 bb = *(const float4*)(b + c);
    float4 r = make_float4(acc.x * s + bb.x, acc.y * s + bb.y,
                           acc.z * s + bb.z, acc.w * s + bb.w);
    *(float4*)(out + (long)d * 128 + c) = r;
}

// ============ launch ============

extern "C" void kernel_launch(void* const* d_in, const int* in_sizes, int n_in,
                              void* d_out, int out_size, void* d_ws, size_t ws_size,
                              hipStream_t stream) {
    const float* x  = (const float*)d_in[0];
    const int*   ei = (const int*)d_in[1];
    // d_in[2] = edge_attr (unused; GCN edge weight = 1)
    const float* W  = (const float*)d_in[3];
    const float* b  = (const float*)d_in[4];
    float* out = (float*)d_out;

    const int N = in_sizes[0] / 128;
    const int E = in_sizes[1] / 2;
    const int* src = ei;
    const int* dst = ei + E;
    const int NB = (N + 255) >> BSH;   // 391 buckets (<= 512)

    // ---- workspace carve (~40 MB) ----
    char* p = (char*)d_ws;
    auto carve = [&](size_t bytes) { char* q = p; p += (bytes + 255) & ~(size_t)255; return q; };
    int*            blockhist  = (int*)           carve((size_t)NBLK * 512 * 4);
    int*            bbase      = (int*)           carve(513 * 4);
    int*            offsets    = (int*)           carve((size_t)(N + 1) * 4);
    float*          dinv       = (float*)         carve((size_t)N * 4);
    unsigned*       packed     = (unsigned*)      carve((size_t)E * 4);
    int*            sorted_src = (int*)           carve((size_t)E * 4);
    unsigned short* g          = (unsigned short*)carve((size_t)N * 128 * 2);

    k_bhist   <<<NBLK, TPB, 0, stream>>>(dst, blockhist, E);
    k_bscan   <<<1, 512, 0, stream>>>(blockhist, bbase, E);
    k_bscatter<<<NBLK, TPB, 0, stream>>>(src, dst, blockhist, bbase, packed, E);
    k_bcsr    <<<NB, TPB, 0, stream>>>(packed, bbase, offsets, sorted_src, dinv, N, E);

    k_gemm<<<(N + 63) / 64, TPB, 0, stream>>>(x, W, dinv, g, N);

    k_aggregate<<<(N + (TPB / 32) - 1) / (TPB / 32), TPB, 0, stream>>>(
        sorted_src, offsets, g, dinv, b, out, N);
}